// Round 13
// baseline (997.512 us; speedup 1.0000x reference)
//
#include <hip/hip_runtime.h>
#include <hip/hip_bf16.h>
#include <math.h>

typedef __bf16 bf16;
typedef __bf16 bf16x4 __attribute__((ext_vector_type(4)));
typedef __bf16 bf16x8 __attribute__((ext_vector_type(8)));
typedef float f32x4 __attribute__((ext_vector_type(4)));

__device__ __forceinline__ void gload_lds16(const bf16* g, bf16* l) {
  __builtin_amdgcn_global_load_lds(
      (const __attribute__((address_space(1))) void*)g,
      (__attribute__((address_space(3))) void*)l, 16, 0, 0);
}

#define MF(a, b, c) __builtin_amdgcn_mfma_f32_16x16x32_bf16((a), (b), (c), 0, 0, 0)
// fused wait+barrier blocks (opaque: nothing can be scheduled across)
#define VM4_BAR()  asm volatile("s_waitcnt vmcnt(4)\ns_barrier" ::: "memory")
#define VM2_BAR()  asm volatile("s_waitcnt vmcnt(2)\ns_barrier" ::: "memory")
#define VM0_BAR()  asm volatile("s_waitcnt vmcnt(0)\ns_barrier" ::: "memory")
#define SFENCE()   __builtin_amdgcn_sched_barrier(0)

// 256x256 8-wave GEMM, BK=64, [256][64] LDS tiles (128B rows, 0-conflict
// chunk-XOR swizzle), double-buffered. m201-style READ-AHEAD schedule:
// each phase's ds_reads fetch the NEXT phase's fragments, so every MFMA
// cluster's operands were loaded >=1 phase earlier (auto counted-lgkm
// already satisfied -> LDS reads overlap MFMA instead of gating it).
// vmcnt ledger: all waits vmcnt(2); stage order pinned by sched_barrier(0).
// C = A[M,K] @ BT[N,K]^T, bf16 in, fp32 accum.
// EPI 0: bf16 = acc+bias | 1: f32 = acc+bias+res | 2: bf16 = gelu(acc+bias)
// EPI 3: bf16 = acc (raw partial; KSPLIT=2) | 4: bf16 = (acc+bias)*(col<1024?SCLQ:1)
template <int EPI, int KSPLIT>
__global__ __launch_bounds__(512, 2)
void gemmq(const bf16* __restrict__ A, const bf16* __restrict__ BT,
           const float* __restrict__ bias, const float* __restrict__ res,
           void* __restrict__ Cout, void* __restrict__ Cout2,
           int M, int N, int K)
{
  __shared__ alignas(16) bf16 lsA[2][16384];   // [buf][256*64]  32KB each
  __shared__ alignas(16) bf16 lsB[2][16384];

  int nbn = N >> 8;
  int nwg = (M >> 8) * nbn;
  int bid = blockIdx.x;
  int ks = 0;
  if (KSPLIT == 2) { ks = (bid >= nwg) ? 1 : 0; bid -= ks * nwg; }
  int cpx = nwg >> 3;
  int wg  = (bid & 7) * cpx + (bid >> 3);      // XCD swizzle (bijective)
  int m0 = (wg / nbn) << 8;
  int n0 = (wg % nbn) << 8;

  int t = threadIdx.x;
  int l = t & 63, w = t >> 6;
  int wr = (w >> 2) << 6;        // 0 / 64   (M within half)
  int wc = (w & 3) << 5;         // 0/32/64/96 (N within half)
  int lr = l & 15, lg = l >> 4;

  int kb0 = (KSPLIT == 2) ? ks * (K >> 1) : 0;
  int nt = (K / KSPLIT) >> 6;    // always even for our shapes

  const bf16* Ag = A  + (size_t)m0 * K + kb0;
  const bf16* Bg = BT + (size_t)n0 * K + kb0;

  // ds_read element offsets: chunk8 = (kk*4+lg) ^ (lr&7)  [0-conflict]
  int swz0 = (lg ^ (lr & 7)) << 3;     // kk=0 chunk, elements
  int swz1 = swz0 ^ 32;                // kk=1 (chunk^4)
  int aRow = (wr + lr) << 6;           // row*64 elements
  int bRow = (wc + lr) << 6;

  // staging: half = 128 rows = 2 x 1024B linear dest; inverse-swz source
  const bf16* srcA[2]; const bf16* srcB[2];
#pragma unroll
  for (int j = 0; j < 2; ++j) {
    int ci = j * 512 + t;
    int r = ci >> 3;
    int g = (ci & 7) ^ (r & 7);
    srcA[j] = Ag + (size_t)r * K + g * 8;
    srcB[j] = Bg + (size_t)r * K + g * 8;
  }
  size_t qA = (size_t)128 * K;         // half-1 source row offset

#define STAGE_A(q, kofs, db) do { \
  _Pragma("unroll") \
  for (int j = 0; j < 2; ++j) \
    gload_lds16(srcA[j] + (q) * qA + (kofs), &lsA[db][(q) * 8192 + (j * 512 + t) * 8]); \
  SFENCE(); \
} while (0)
#define STAGE_B(q, kofs, db) do { \
  _Pragma("unroll") \
  for (int j = 0; j < 2; ++j) \
    gload_lds16(srcB[j] + (q) * qA + (kofs), &lsB[db][(q) * 8192 + (j * 512 + t) * 8]); \
  SFENCE(); \
} while (0)

  f32x4 acc[2][2][4][2];
  f32x4 zero = {0.f, 0.f, 0.f, 0.f};
#pragma unroll
  for (int qa = 0; qa < 2; ++qa)
#pragma unroll
    for (int qb = 0; qb < 2; ++qb)
#pragma unroll
      for (int mi = 0; mi < 4; ++mi)
#pragma unroll
        for (int ni = 0; ni < 2; ++ni) acc[qa][qb][mi][ni] = zero;

  // prologue: stage tile 0 (A0,B0,B1,A1); drain A0,B0; pre-read their frags
  STAGE_A(0, 0, 0);
  STAGE_B(0, 0, 0);
  STAGE_B(1, 0, 0);
  STAGE_A(1, 0, 0);
  VM4_BAR();                           // A0(0),B0(0) resident (all waves)

  bf16x8 a0A[4][2], a0B[4][2], b0A[2][2], b0B[2][2];   // read-ahead sets
  bf16x8 afr1[4][2], bfr1[2][2];

#pragma unroll
  for (int mi = 0; mi < 4; ++mi) {
    a0A[mi][0] = *(const bf16x8*)(&lsA[0][0] + aRow + mi * 1024 + swz0);
    a0A[mi][1] = *(const bf16x8*)(&lsA[0][0] + aRow + mi * 1024 + swz1);
  }
#pragma unroll
  for (int ni = 0; ni < 2; ++ni) {
    b0A[ni][0] = *(const bf16x8*)(&lsB[0][0] + bRow + ni * 1024 + swz0);
    b0A[ni][1] = *(const bf16x8*)(&lsB[0][0] + bRow + ni * 1024 + swz1);
  }

// one K-tile: phases compute with regs read LAST phase; reads fetch NEXT.
#define TILE_BODY(TT, CB, A0C, B0C, A0N, B0N) do { \
  const bf16* pa = &lsA[CB][0]; \
  const bf16* pb = &lsB[CB][0]; \
  const int DB = (CB) ^ 1; \
  bool st = ((TT) + 1 < nt); \
  int k64 = ((TT) + 1) << 6; \
  /* ---- ph0: MFMA Q(0,0); read B1(T); stage A0(T+1) ---- */ \
  VM2_BAR(); \
  _Pragma("unroll") \
  for (int ni = 0; ni < 2; ++ni) { \
    bfr1[ni][0] = *(const bf16x8*)(pb + 8192 + bRow + ni * 1024 + swz0); \
    bfr1[ni][1] = *(const bf16x8*)(pb + 8192 + bRow + ni * 1024 + swz1); \
  } \
  if (st) STAGE_A(0, k64, DB); \
  __builtin_amdgcn_s_setprio(1); \
  _Pragma("unroll") \
  for (int mi = 0; mi < 4; ++mi) \
    _Pragma("unroll") \
    for (int ni = 0; ni < 2; ++ni) \
      _Pragma("unroll") \
      for (int kk = 0; kk < 2; ++kk) \
        acc[0][0][mi][ni] = MF(A0C[mi][kk], B0C[ni][kk], acc[0][0][mi][ni]); \
  __builtin_amdgcn_s_setprio(0); \
  /* ---- ph1: MFMA Q(0,1); read A1(T); stage B0(T+1) ---- */ \
  if (st) VM2_BAR(); else VM0_BAR(); \
  _Pragma("unroll") \
  for (int mi = 0; mi < 4; ++mi) { \
    afr1[mi][0] = *(const bf16x8*)(pa + 8192 + aRow + mi * 1024 + swz0); \
    afr1[mi][1] = *(const bf16x8*)(pa + 8192 + aRow + mi * 1024 + swz1); \
  } \
  if (st) STAGE_B(0, k64, DB); \
  __builtin_amdgcn_s_setprio(1); \
  _Pragma("unroll") \
  for (int mi = 0; mi < 4; ++mi) \
    _Pragma("unroll") \
    for (int ni = 0; ni < 2; ++ni) \
      _Pragma("unroll") \
      for (int kk = 0; kk < 2; ++kk) \
        acc[0][1][mi][ni] = MF(A0C[mi][kk], bfr1[ni][kk], acc[0][1][mi][ni]); \
  __builtin_amdgcn_s_setprio(0); \
  /* ---- ph2: MFMA Q(1,1); stage B1(T+1); no barrier ---- */ \
  if (st) STAGE_B(1, k64, DB); \
  __builtin_amdgcn_s_setprio(1); \
  _Pragma("unroll") \
  for (int mi = 0; mi < 4; ++mi) \
    _Pragma("unroll") \
    for (int ni = 0; ni < 2; ++ni) \
      _Pragma("unroll") \
      for (int kk = 0; kk < 2; ++kk) \
        acc[1][1][mi][ni] = MF(afr1[mi][kk], bfr1[ni][kk], acc[1][1][mi][ni]); \
  __builtin_amdgcn_s_setprio(0); \
  /* ---- ph3: MFMA Q(1,0); read A0/B0(T+1) from next buf; stage A1(T+1) */ \
  if (st) { \
    VM2_BAR(); \
    _Pragma("unroll") \
    for (int mi = 0; mi < 4; ++mi) { \
      A0N[mi][0] = *(const bf16x8*)(&lsA[DB][0] + aRow + mi * 1024 + swz0); \
      A0N[mi][1] = *(const bf16x8*)(&lsA[DB][0] + aRow + mi * 1024 + swz1); \
    } \
    _Pragma("unroll") \
    for (int ni = 0; ni < 2; ++ni) { \
      B0N[ni][0] = *(const bf16x8*)(&lsB[DB][0] + bRow + ni * 1024 + swz0); \
      B0N[ni][1] = *(const bf16x8*)(&lsB[DB][0] + bRow + ni * 1024 + swz1); \
    } \
    STAGE_A(1, k64, DB); \
  } \
  __builtin_amdgcn_s_setprio(1); \
  _Pragma("unroll") \
  for (int mi = 0; mi < 4; ++mi) \
    _Pragma("unroll") \
    for (int ni = 0; ni < 2; ++ni) \
      _Pragma("unroll") \
      for (int kk = 0; kk < 2; ++kk) \
        acc[1][0][mi][ni] = MF(afr1[mi][kk], B0C[ni][kk], acc[1][0][mi][ni]); \
  __builtin_amdgcn_s_setprio(0); \
} while (0)

  for (int T = 0; T < nt; T += 2) {
    TILE_BODY(T,     0, a0A, b0A, a0B, b0B);
    TILE_BODY(T + 1, 1, a0B, b0B, a0A, b0A);
  }

  // epilogue
  const float SCLQ = 0.18033688011112042f;   // 0.125 * log2(e)
  bf16* Pb = (bf16*)((KSPLIT == 2 && ks) ? Cout2 : Cout);
#pragma unroll
  for (int qa = 0; qa < 2; ++qa)
#pragma unroll
    for (int mi = 0; mi < 4; ++mi) {
      int row = m0 + qa * 128 + wr + mi * 16 + lg * 4;
#pragma unroll
      for (int qb = 0; qb < 2; ++qb)
#pragma unroll
        for (int ni = 0; ni < 2; ++ni) {
          int col = n0 + qb * 128 + wc + ni * 16 + lr;
          float bv = (EPI == 3) ? 0.f : bias[col];
          f32x4 a = acc[qa][qb][mi][ni];
#pragma unroll
          for (int r = 0; r < 4; ++r) {
            float v = a[r] + bv;
            size_t idx = (size_t)(row + r) * N + col;
            if (EPI == 0)      Pb[idx] = (bf16)v;
            else if (EPI == 1) ((float*)Cout)[idx] = v + res[idx];
            else if (EPI == 2) Pb[idx] = (bf16)(0.5f * v * (1.f + erff(v * 0.70710678118654752f)));
            else if (EPI == 4) Pb[idx] = (bf16)((col < 1024) ? v * SCLQ : v);
            else               Pb[idx] = (bf16)v;
          }
        }
    }
#undef STAGE_A
#undef STAGE_B
#undef TILE_BODY
}

// out = p0 + p1 + bias + res (f32), for split-K. 8 elems/thread, N=1024.
__global__ __launch_bounds__(256)
void combine2(const bf16* __restrict__ p0, const bf16* __restrict__ p1,
              const float* __restrict__ bias, const float* __restrict__ res,
              float* __restrict__ out)
{
  int i = (blockIdx.x * 256 + threadIdx.x) * 8;
  bf16x8 a = *(const bf16x8*)(p0 + i);
  bf16x8 b = *(const bf16x8*)(p1 + i);
  int c = i & 1023;
#pragma unroll
  for (int j = 0; j < 8; ++j)
    out[i + j] = (float)a[j] + (float)b[j] + bias[c + j] + res[i + j];
}

// Fused: x1 = p0+p1+bias+res (f32 out), h = LN(x1)*w+b (bf16 out).
__global__ __launch_bounds__(256)
void combine_ln(const bf16* __restrict__ p0, const bf16* __restrict__ p1,
                const float* __restrict__ bias, const float* __restrict__ res,
                const float* __restrict__ lnw, const float* __restrict__ lnb,
                float* __restrict__ x1, bf16* __restrict__ hout)
{
  int row = blockIdx.x;
  int t = threadIdx.x;
  size_t i0 = (size_t)row * 1024 + t * 4;
  bf16x4 a = *(const bf16x4*)(p0 + i0);
  bf16x4 b = *(const bf16x4*)(p1 + i0);
  float4 r = *(const float4*)(res + i0);
  float4 bi = ((const float4*)bias)[t];
  float v0 = (float)a[0] + (float)b[0] + bi.x + r.x;
  float v1 = (float)a[1] + (float)b[1] + bi.y + r.y;
  float v2 = (float)a[2] + (float)b[2] + bi.z + r.z;
  float v3 = (float)a[3] + (float)b[3] + bi.w + r.w;
  float4 vv = {v0, v1, v2, v3};
  *(float4*)(x1 + i0) = vv;
  float s  = v0 + v1 + v2 + v3;
  float sq = v0 * v0 + v1 * v1 + v2 * v2 + v3 * v3;
#pragma unroll
  for (int off = 32; off >= 1; off >>= 1) {
    s  += __shfl_xor(s, off);
    sq += __shfl_xor(sq, off);
  }
  __shared__ float ps[4], pq[4];
  if ((t & 63) == 0) { ps[t >> 6] = s; pq[t >> 6] = sq; }
  __syncthreads();
  s  = ps[0] + ps[1] + ps[2] + ps[3];
  sq = pq[0] + pq[1] + pq[2] + pq[3];
  float mu  = s * (1.f / 1024.f);
  float var = sq * (1.f / 1024.f) - mu * mu;
  float rstd = rsqrtf(var + 1e-5f);
  float4 wv = ((const float4*)lnw)[t];
  float4 bv = ((const float4*)lnb)[t];
  hout[i0 + 0] = (bf16)((v0 - mu) * rstd * wv.x + bv.x);
  hout[i0 + 1] = (bf16)((v1 - mu) * rstd * wv.y + bv.y);
  hout[i0 + 2] = (bf16)((v2 - mu) * rstd * wv.z + bv.z);
  hout[i0 + 3] = (bf16)((v3 - mu) * rstd * wv.w + bv.w);
}

// LayerNorm over last dim (1024), fp32 in -> bf16 out. One block per row.
__global__ __launch_bounds__(256)
void ln_bf16(const float* __restrict__ x, const float* __restrict__ w,
             const float* __restrict__ b, bf16* __restrict__ out)
{
  int row = blockIdx.x;
  int t = threadIdx.x;
  float4 v = ((const float4*)(x + (size_t)row * 1024))[t];
  float s  = v.x + v.y + v.z + v.w;
  float sq = v.x * v.x + v.y * v.y + v.z * v.z + v.w * v.w;
#pragma unroll
  for (int off = 32; off >= 1; off >>= 1) {
    s  += __shfl_xor(s, off);
    sq += __shfl_xor(sq, off);
  }
  __shared__ float ps[4], pq[4];
  if ((t & 63) == 0) { ps[t >> 6] = s; pq[t >> 6] = sq; }
  __syncthreads();
  s  = ps[0] + ps[1] + ps[2] + ps[3];
  sq = pq[0] + pq[1] + pq[2] + pq[3];
  float mu  = s * (1.f / 1024.f);
  float var = sq * (1.f / 1024.f) - mu * mu;
  float rstd = rsqrtf(var + 1e-5f);
  float4 wv = ((const float4*)w)[t];
  float4 bv = ((const float4*)b)[t];
  size_t o0 = (size_t)row * 1024 + t * 4;
  out[o0 + 0] = (bf16)((v.x - mu) * rstd * wv.x + bv.x);
  out[o0 + 1] = (bf16)((v.y - mu) * rstd * wv.y + bv.y);
  out[o0 + 2] = (bf16)((v.z - mu) * rstd * wv.z + bv.z);
  out[o0 + 3] = (bf16)((v.w - mu) * rstd * wv.w + bv.w);
}

// WT[N,K] (bf16) = W[K,N] (f32) transposed+cast. grid=(K/32, N/32), 256 thr.
__global__ __launch_bounds__(256)
void transpose_cast(const float* __restrict__ W, bf16* __restrict__ WT, int K, int N)
{
  __shared__ float tile[32][33];
  int bk = blockIdx.x * 32, bn = blockIdx.y * 32;
  int tx = threadIdx.x & 31, ty = threadIdx.x >> 5;
#pragma unroll
  for (int i = ty; i < 32; i += 8)
    tile[i][tx] = W[(size_t)(bk + i) * N + bn + tx];
  __syncthreads();
#pragma unroll
  for (int i = ty; i < 32; i += 8)
    WT[(size_t)(bn + i) * K + bk + tx] = (bf16)tile[tx][i];
}

// V transpose: vt[(b*16+h)*64 + d][t] = qkv[(b*2048+t)*3072 + 2048 + h*64 + d]
__global__ __launch_bounds__(256)
void vtrans(const bf16* __restrict__ qkv, bf16* __restrict__ vt)
{
  __shared__ alignas(16) bf16 tile[64 * 64];
  int bh = blockIdx.x;
  int b = bh >> 4, h = bh & 15;
  int t0 = blockIdx.y * 64;
  int t = threadIdx.x;
#pragma unroll
  for (int i = 0; i < 2; ++i) {
    int c = i * 256 + t;
    int tt = c >> 3, d8 = c & 7;
    bf16x8 v = *(const bf16x8*)(qkv + (size_t)(b * 2048 + t0 + tt) * 3072 + 2048 + h * 64 + d8 * 8);
    *(bf16x8*)&tile[(tt * 8 + (d8 ^ (tt >> 3))) * 8] = v;
  }
  __syncthreads();
#pragma unroll
  for (int i = 0; i < 2; ++i) {
    int c = i * 256 + t;
    int d = c >> 3, tt8 = c & 7;
    bf16x8 o;
#pragma unroll
    for (int j = 0; j < 8; ++j) {
      int row = tt8 * 8 + j;
      o[j] = tile[(row * 8 + ((d >> 3) ^ (row >> 3))) * 8 + (d & 7)];
    }
    *(bf16x8*)(vt + (size_t)(bh * 64 + d) * 2048 + t0 + tt8 * 8) = o;
  }
}

// Flash causal attention, 8-wave blocks (QBLK=128), fixed-cap softmax
// (Q pre-scaled by 0.125*log2e in qkv epilogue). Double-buffered K/V
// staging shared by 8 waves; single fused vmcnt(0)+barrier per tile.
__global__ __launch_bounds__(512)
void attn_flash(const bf16* __restrict__ qkv, const bf16* __restrict__ vt,
                bf16* __restrict__ y)
{
  __shared__ alignas(16) bf16 lk[2][4096];
  __shared__ alignas(16) bf16 lv[2][4096];
  __shared__ alignas(16) bf16 lp[8][16 * 64];

  int bid = blockIdx.x;
  int bh = bid & 63;
  int qb = 15 - (bid >> 6);            // big q-blocks first
  int b = bh >> 4, h = bh & 15;
  int t = threadIdx.x;
  int w = t >> 6, l = t & 63;
  int lr = l & 15, lg = l >> 4;
  int q0 = qb * 128;
  int qw = q0 + w * 16;
  const size_t RS = 3072;

  const bf16* qbase = qkv + (size_t)(b * 2048) * RS + h * 64;
  const bf16* kbase = qkv + (size_t)(b * 2048) * RS + 1024 + h * 64;
  const bf16* vtb   = vt + (size_t)(bh * 64) * 2048;

  bf16x8 qf[2];
#pragma unroll
  for (int kk = 0; kk < 2; ++kk)
    qf[kk] = *(const bf16x8*)(qbase + (size_t)(qw + lr) * RS + kk * 32 + lg * 8);

  // per-thread staging: 1 chunk of K-tile + 1 chunk of V^T-tile (512 thr)
  int row = t >> 3, c8 = t & 7;
  int sc8 = c8 ^ (row & 7);
  const bf16* pK = kbase + (size_t)row * RS + sc8 * 8;
  const bf16* pV = vtb + (size_t)row * 2048 + sc8 * 8;
  int dst = t * 8;

  f32x4 zero = {0.f, 0.f, 0.f, 0.f};
  f32x4 o[4];
#pragma unroll
  for (int ni = 0; ni < 4; ++ni) o[ni] = zero;
  float lo[4] = {0.f, 0.f, 0.f, 0.f};

  int nkb = 2 * qb + 2;
  gload_lds16(pK, &lk[0][dst]);
  gload_lds16(pV, &lv[0][dst]);

  for (int kb = 0; kb < nkb; ++kb) {
    int cur = kb & 1;
    int k0 = kb * 64;
    VM0_BAR();
    if (kb + 1 < nkb) {
      pK += 64 * RS;
      pV += 64;
      gload_lds16(pK, &lk[cur ^ 1][dst]);
      gload_lds16(pV, &lv[cur ^ 1][dst]);
    }

    f32x4 s[4];
#pragma unroll
    for (int j = 0; j < 4; ++j) s[j] = zero;
#pragma unroll
    for (int kk = 0; kk < 2; ++kk)
#pragma unroll
      for (int j = 0; j < 4; ++j) {
        int krow = j * 16 + lr;
        bf16x8 kf = *(const bf16x8*)&lk[cur][krow * 64 + (((4 * kk + lg) ^ (krow & 7)) * 8)];
        s[j] = MF(qf[kk], kf, s[j]);
      }

    bool needmask = (k0 + 63 > qw);    // wave-uniform
    float p[4][4];
#pragma unroll
    for (int r = 0; r < 4; ++r) {
      int tq = qw + lg * 4 + r;
#pragma unroll
      for (int j = 0; j < 4; ++j) {
        float v = s[j][r];
        if (needmask && (k0 + j * 16 + lr > tq)) v = -1e30f;
        p[j][r] = exp2f(v);
      }
      lo[r] += (p[0][r] + p[1][r]) + (p[2][r] + p[3][r]);
    }

#pragma unroll
    for (int r = 0; r < 4; ++r) {
      int qr = lg * 4 + r;
#pragma unroll
      for (int j = 0; j < 4; ++j) {
        int ch = (2 * j + (lr >> 3)) ^ (qr & 7);
        lp[w][qr * 64 + ch * 8 + (lr & 7)] = (bf16)p[j][r];
      }
    }
    bf16x8 pa[2];
#pragma unroll
    for (int kf = 0; kf < 2; ++kf)
      pa[kf] = *(const bf16x8*)&lp[w][lr * 64 + (((4 * kf + lg) ^ (lr & 7)) * 8)];

#pragma unroll
    for (int ni = 0; ni < 4; ++ni)
#pragma unroll
      for (int kf = 0; kf < 2; ++kf) {
        int d = ni * 16 + lr;
        bf16x8 vf = *(const bf16x8*)&lv[cur][d * 64 + (((4 * kf + lg) ^ (d & 7)) * 8)];
        o[ni] = MF(pa[kf], vf, o[ni]);
      }
  }

#pragma unroll
  for (int r = 0; r < 4; ++r) {
#pragma unroll
    for (int off = 1; off < 16; off <<= 1) lo[r] += __shfl_xor(lo[r], off);
    lo[r] = 1.f / lo[r];
  }
#pragma unroll
  for (int ni = 0; ni < 4; ++ni)
#pragma unroll
    for (int r = 0; r < 4; ++r) {
      int tq = qw + lg * 4 + r;
      y[(size_t)(b * 2048 + tq) * 1024 + h * 64 + ni * 16 + lr] = (bf16)(o[ni][r] * lo[r]);
    }
}

extern "C" void kernel_launch(void* const* d_in, const int* in_sizes, int n_in,
                              void* d_out, int out_size, void* d_ws, size_t ws_size,
                              hipStream_t stream) {
  (void)in_sizes; (void)n_in; (void)out_size; (void)ws_size;
  const float* x      = (const float*)d_in[0];
  const float* ln1w   = (const float*)d_in[1];
  const float* ln1b   = (const float*)d_in[2];
  const float* ln2w   = (const float*)d_in[3];
  const float* ln2b   = (const float*)d_in[4];
  const float* w_attn = (const float*)d_in[5];
  const float* b_attn = (const float*)d_in[6];
  const float* w_proj = (const float*)d_in[7];
  const float* b_proj = (const float*)d_in[8];
  const float* w_fc   = (const float*)d_in[9];
  const float* b_fc   = (const float*)d_in[10];
  const float* w_fc2  = (const float*)d_in[11];
  const float* b_fc2  = (const float*)d_in[12];
  float* out = (float*)d_out;

  // workspace: h | [qkv | y] == m | x1 (vt overlays x1) | weightsT
  char* p = (char*)d_ws;
  bf16*  h     = (bf16*)p;  p += (size_t)8192 * 1024 * 2;
  bf16*  qkv   = (bf16*)p;
  bf16*  mbuf  = (bf16*)p;  p += (size_t)8192 * 3072 * 2;   // m overlays qkv+y
  bf16*  ybuf  = (bf16*)p;  p += (size_t)8192 * 1024 * 2;
  float* x1    = (float*)p; p += (size_t)8192 * 1024 * 4;
  bf16*  wqkvT = (bf16*)p;  p += (size_t)3072 * 1024 * 2;
  bf16*  wprojT= (bf16*)p;  p += (size_t)1024 * 1024 * 2;
  bf16*  wfcT  = (bf16*)p;  p += (size_t)4096 * 1024 * 2;
  bf16*  wfc2T = (bf16*)p;  p += (size_t)1024 * 4096 * 2;
  bf16*  vt    = (bf16*)x1;       // dead until combine_ln writes x1
  bf16*  pp0   = qkv;             // proj split-K partials (qkv dead post-attn)
  bf16*  pp1   = qkv + (size_t)8192 * 1024;
  bf16*  sp0   = h;               // fc2 split-K partials
  bf16*  sp1   = wqkvT;

  transpose_cast<<<dim3(1024 / 32, 3072 / 32), 256, 0, stream>>>(w_attn, wqkvT, 1024, 3072);
  transpose_cast<<<dim3(1024 / 32, 1024 / 32), 256, 0, stream>>>(w_proj, wprojT, 1024, 1024);
  transpose_cast<<<dim3(1024 / 32, 4096 / 32), 256, 0, stream>>>(w_fc,   wfcT,  1024, 4096);
  transpose_cast<<<dim3(4096 / 32, 1024 / 32), 256, 0, stream>>>(w_fc2,  wfc2T, 4096, 1024);

  ln_bf16<<<8192, 256, 0, stream>>>(x, ln1w, ln1b, h);
  gemmq<4, 1><<<384, 512, 0, stream>>>(h, wqkvT, b_attn, nullptr, qkv, nullptr, 8192, 3072, 1024);
  vtrans<<<dim3(64, 32), 256, 0, stream>>>(qkv, vt);
  attn_flash<<<1024, 512, 0, stream>>>(qkv, vt, ybuf);
  gemmq<3, 2><<<256, 512, 0, stream>>>(ybuf, wprojT, nullptr, nullptr, pp0, pp1, 8192, 1024, 1024);
  combine_ln<<<8192, 256, 0, stream>>>(pp0, pp1, b_proj, x, ln2w, ln2b, x1, h);
  gemmq<2, 1><<<512, 512, 0, stream>>>(h, wfcT, b_fc, nullptr, mbuf, nullptr, 8192, 4096, 1024);
  gemmq<3, 2><<<256, 512, 0, stream>>>(mbuf, wfc2T, nullptr, nullptr, sp0, sp1, 8192, 1024, 4096);
  combine2<<<4096, 256, 0, stream>>>(sp0, sp1, b_fc2, x1, out);
}

// Round 14
// 421.120 us; speedup vs baseline: 2.3687x; 2.3687x over previous
//
#include <hip/hip_runtime.h>
#include <hip/hip_bf16.h>
#include <math.h>

typedef __bf16 bf16;
typedef __bf16 bf16x4 __attribute__((ext_vector_type(4)));
typedef __bf16 bf16x8 __attribute__((ext_vector_type(8)));
typedef float f32x4 __attribute__((ext_vector_type(4)));

__device__ __forceinline__ void gload_lds16(const bf16* g, bf16* l) {
  __builtin_amdgcn_global_load_lds(
      (const __attribute__((address_space(1))) void*)g,
      (__attribute__((address_space(3))) void*)l, 16, 0, 0);
}

#define MF(a, b, c) __builtin_amdgcn_mfma_f32_16x16x32_bf16((a), (b), (c), 0, 0, 0)
// fused wait+barrier blocks (opaque: no memory op can cross)
#define VM4_BAR()  asm volatile("s_waitcnt vmcnt(4)\ns_barrier" ::: "memory")
#define VM2_BAR()  asm volatile("s_waitcnt vmcnt(2)\ns_barrier" ::: "memory")
#define VM0_BAR()  asm volatile("s_waitcnt vmcnt(0)\ns_barrier" ::: "memory")

// 256x256 8-wave GEMM, BK=64, [256][64] LDS tiles (128B rows, 0-conflict
// chunk-XOR swizzle), double-buffered. ROTATED schedule: every MFMA cluster
// consumes fragments ds_read in the PREVIOUS phase (compiler inserts exact
// counted lgkmcnt; no phase-gating lgkmcnt(0)). Cross-tile A0/B0 reads land
// after Q(1,0)'s MFMA into the SAME registers (WAR, zero extra VGPR).
// vmcnt ledger: VM2 at phases A/B/D (leaves exactly the not-yet-needed
// half in flight); VM0 at B of last tile. C = A[M,K] @ BT[N,K]^T.
// EPI 0: bf16 = acc+bias | 1: f32 = acc+bias+res | 2: bf16 = gelu(acc+bias)
// EPI 3: bf16 = acc (raw partial; KSPLIT=2) | 4: bf16 = (acc+bias)*(col<1024?SCLQ:1)
template <int EPI, int KSPLIT>
__global__ __launch_bounds__(512, 2)
void gemmq(const bf16* __restrict__ A, const bf16* __restrict__ BT,
           const float* __restrict__ bias, const float* __restrict__ res,
           void* __restrict__ Cout, void* __restrict__ Cout2,
           int M, int N, int K)
{
  __shared__ alignas(16) bf16 lsA[2][16384];   // [buf][256*64]  32KB each
  __shared__ alignas(16) bf16 lsB[2][16384];

  int nbn = N >> 8;
  int nwg = (M >> 8) * nbn;
  int bid = blockIdx.x;
  int ks = 0;
  if (KSPLIT == 2) { ks = (bid >= nwg) ? 1 : 0; bid -= ks * nwg; }
  int cpx = nwg >> 3;
  int wg  = (bid & 7) * cpx + (bid >> 3);      // XCD swizzle (bijective)
  int m0 = (wg / nbn) << 8;
  int n0 = (wg % nbn) << 8;

  int t = threadIdx.x;
  int l = t & 63, w = t >> 6;
  int wr = (w >> 2) << 6;        // 0 / 64   (M within half)
  int wc = (w & 3) << 5;         // 0/32/64/96 (N within half)
  int lr = l & 15, lg = l >> 4;

  int kb0 = (KSPLIT == 2) ? ks * (K >> 1) : 0;
  int nt = (K / KSPLIT) >> 6;

  const bf16* Ag = A  + (size_t)m0 * K + kb0;
  const bf16* Bg = BT + (size_t)n0 * K + kb0;

  // ds_read element offsets: chunk8 = (kk*4+lg) ^ (lr&7)  [0-conflict]
  int swz0 = (lg ^ (lr & 7)) << 3;     // kk=0 chunk, elements
  int swz1 = swz0 ^ 32;                // kk=1 (chunk^4)
  int aRow = (wr + lr) << 6;           // row*64 elements
  int bRow = (wc + lr) << 6;

  // staging: half = 128 rows = 2 x 1024B linear dest; inverse-swz source
  const bf16* srcA[2]; const bf16* srcB[2];
#pragma unroll
  for (int j = 0; j < 2; ++j) {
    int ci = j * 512 + t;
    int r = ci >> 3;
    int g = (ci & 7) ^ (r & 7);
    srcA[j] = Ag + (size_t)r * K + g * 8;
    srcB[j] = Bg + (size_t)r * K + g * 8;
  }
  size_t qA = (size_t)128 * K;         // half-1 source row offset

#define STAGE_A(q, kofs, db) do { \
  _Pragma("unroll") \
  for (int j = 0; j < 2; ++j) \
    gload_lds16(srcA[j] + (q) * qA + (kofs), &lsA[db][(q) * 8192 + (j * 512 + t) * 8]); \
} while (0)
#define STAGE_B(q, kofs, db) do { \
  _Pragma("unroll") \
  for (int j = 0; j < 2; ++j) \
    gload_lds16(srcB[j] + (q) * qA + (kofs), &lsB[db][(q) * 8192 + (j * 512 + t) * 8]); \
} while (0)

  f32x4 acc[2][2][4][2];
  f32x4 zero = {0.f, 0.f, 0.f, 0.f};
#pragma unroll
  for (int qa = 0; qa < 2; ++qa)
#pragma unroll
    for (int qb = 0; qb < 2; ++qb)
#pragma unroll
      for (int mi = 0; mi < 4; ++mi)
#pragma unroll
        for (int ni = 0; ni < 2; ++ni) acc[qa][qb][mi][ni] = zero;

  // prologue: stage tile 0 (A0,B0,B1,A1); wait A0,B0; pre-read their frags
  STAGE_A(0, 0, 0);
  STAGE_B(0, 0, 0);
  STAGE_B(1, 0, 0);
  STAGE_A(1, 0, 0);
  VM4_BAR();                           // A0(0),B0(0) resident (all waves)

  bf16x8 a0[4][2], bfr0[2][2], afr1[4][2], bfr1[2][2];
#pragma unroll
  for (int mi = 0; mi < 4; ++mi) {
    a0[mi][0] = *(const bf16x8*)(&lsA[0][0] + aRow + mi * 1024 + swz0);
    a0[mi][1] = *(const bf16x8*)(&lsA[0][0] + aRow + mi * 1024 + swz1);
  }
#pragma unroll
  for (int ni = 0; ni < 2; ++ni) {
    bfr0[ni][0] = *(const bf16x8*)(&lsB[0][0] + bRow + ni * 1024 + swz0);
    bfr0[ni][1] = *(const bf16x8*)(&lsB[0][0] + bRow + ni * 1024 + swz1);
  }

  for (int T = 0; T < nt; ++T) {
    int c = T & 1, d = c ^ 1;
    bool st = (T + 1 < nt);
    int k64 = (T + 1) << 6;
    const bf16* pa = &lsA[c][0];
    const bf16* pb = &lsB[c][0];

    // ---- phase A: MFMA Q(0,0) [a0,bfr0: read last phase D]; read B1(T);
    //      stage A0(T+1). VM2 leaves A1(T) in flight.
    VM2_BAR();
#pragma unroll
    for (int ni = 0; ni < 2; ++ni) {
      bfr1[ni][0] = *(const bf16x8*)(pb + 8192 + bRow + ni * 1024 + swz0);
      bfr1[ni][1] = *(const bf16x8*)(pb + 8192 + bRow + ni * 1024 + swz1);
    }
    if (st) STAGE_A(0, k64, d);
    __builtin_amdgcn_s_setprio(1);
#pragma unroll
    for (int mi = 0; mi < 4; ++mi)
#pragma unroll
      for (int ni = 0; ni < 2; ++ni)
#pragma unroll
        for (int kk = 0; kk < 2; ++kk)
          acc[0][0][mi][ni] = MF(a0[mi][kk], bfr0[ni][kk], acc[0][0][mi][ni]);
    __builtin_amdgcn_s_setprio(0);

    // ---- phase B: MFMA Q(0,1) [a0 + bfr1 from phase A]; read A1(T);
    //      stage B0(T+1). VM2 leaves A0(T+1); last tile needs VM0.
    if (st) VM2_BAR(); else VM0_BAR();
#pragma unroll
    for (int mi = 0; mi < 4; ++mi) {
      afr1[mi][0] = *(const bf16x8*)(pa + 8192 + aRow + mi * 1024 + swz0);
      afr1[mi][1] = *(const bf16x8*)(pa + 8192 + aRow + mi * 1024 + swz1);
    }
    if (st) STAGE_B(0, k64, d);
    __builtin_amdgcn_s_setprio(1);
#pragma unroll
    for (int mi = 0; mi < 4; ++mi)
#pragma unroll
      for (int ni = 0; ni < 2; ++ni)
#pragma unroll
        for (int kk = 0; kk < 2; ++kk)
          acc[0][1][mi][ni] = MF(a0[mi][kk], bfr1[ni][kk], acc[0][1][mi][ni]);
    __builtin_amdgcn_s_setprio(0);

    // ---- phase C: MFMA Q(1,1) [afr1 from phase B + bfr1]; stage B1(T+1);
    //      no barrier needed.
    if (st) STAGE_B(1, k64, d);
    __builtin_amdgcn_s_setprio(1);
#pragma unroll
    for (int mi = 0; mi < 4; ++mi)
#pragma unroll
      for (int ni = 0; ni < 2; ++ni)
#pragma unroll
        for (int kk = 0; kk < 2; ++kk)
          acc[1][1][mi][ni] = MF(afr1[mi][kk], bfr1[ni][kk], acc[1][1][mi][ni]);
    __builtin_amdgcn_s_setprio(0);

    // ---- phase D: MFMA Q(1,0) [afr1 + bfr0(T)]; then read A0/B0(T+1)
    //      into the SAME a0/bfr0 regs (WAR after MFMA); stage A1(T+1).
    //      VM2 leaves B1(T+1) in flight.
    if (st) VM2_BAR();
    __builtin_amdgcn_s_setprio(1);
#pragma unroll
    for (int mi = 0; mi < 4; ++mi)
#pragma unroll
      for (int ni = 0; ni < 2; ++ni)
#pragma unroll
        for (int kk = 0; kk < 2; ++kk)
          acc[1][0][mi][ni] = MF(afr1[mi][kk], bfr0[ni][kk], acc[1][0][mi][ni]);
    __builtin_amdgcn_s_setprio(0);
    if (st) {
#pragma unroll
      for (int mi = 0; mi < 4; ++mi) {
        a0[mi][0] = *(const bf16x8*)(&lsA[d][0] + aRow + mi * 1024 + swz0);
        a0[mi][1] = *(const bf16x8*)(&lsA[d][0] + aRow + mi * 1024 + swz1);
      }
#pragma unroll
      for (int ni = 0; ni < 2; ++ni) {
        bfr0[ni][0] = *(const bf16x8*)(&lsB[d][0] + bRow + ni * 1024 + swz0);
        bfr0[ni][1] = *(const bf16x8*)(&lsB[d][0] + bRow + ni * 1024 + swz1);
      }
      STAGE_A(1, k64, d);
    }
  }

  // epilogue
  const float SCLQ = 0.18033688011112042f;   // 0.125 * log2(e)
  bf16* Pb = (bf16*)((KSPLIT == 2 && ks) ? Cout2 : Cout);
#pragma unroll
  for (int qa = 0; qa < 2; ++qa)
#pragma unroll
    for (int mi = 0; mi < 4; ++mi) {
      int row = m0 + qa * 128 + wr + mi * 16 + lg * 4;
#pragma unroll
      for (int qb = 0; qb < 2; ++qb)
#pragma unroll
        for (int ni = 0; ni < 2; ++ni) {
          int col = n0 + qb * 128 + wc + ni * 16 + lr;
          float bv = (EPI == 3) ? 0.f : bias[col];
          f32x4 a = acc[qa][qb][mi][ni];
#pragma unroll
          for (int r = 0; r < 4; ++r) {
            float v = a[r] + bv;
            size_t idx = (size_t)(row + r) * N + col;
            if (EPI == 0)      Pb[idx] = (bf16)v;
            else if (EPI == 1) ((float*)Cout)[idx] = v + res[idx];
            else if (EPI == 2) Pb[idx] = (bf16)(0.5f * v * (1.f + erff(v * 0.70710678118654752f)));
            else if (EPI == 4) Pb[idx] = (bf16)((col < 1024) ? v * SCLQ : v);
            else               Pb[idx] = (bf16)v;
          }
        }
    }
#undef STAGE_A
#undef STAGE_B
}

// out = p0 + p1 + bias + res (f32), for split-K. 8 elems/thread, N=1024.
__global__ __launch_bounds__(256)
void combine2(const bf16* __restrict__ p0, const bf16* __restrict__ p1,
              const float* __restrict__ bias, const float* __restrict__ res,
              float* __restrict__ out)
{
  int i = (blockIdx.x * 256 + threadIdx.x) * 8;
  bf16x8 a = *(const bf16x8*)(p0 + i);
  bf16x8 b = *(const bf16x8*)(p1 + i);
  int c = i & 1023;
#pragma unroll
  for (int j = 0; j < 8; ++j)
    out[i + j] = (float)a[j] + (float)b[j] + bias[c + j] + res[i + j];
}

// Fused: x1 = p0+p1+bias+res (f32 out), h = LN(x1)*w+b (bf16 out).
__global__ __launch_bounds__(256)
void combine_ln(const bf16* __restrict__ p0, const bf16* __restrict__ p1,
                const float* __restrict__ bias, const float* __restrict__ res,
                const float* __restrict__ lnw, const float* __restrict__ lnb,
                float* __restrict__ x1, bf16* __restrict__ hout)
{
  int row = blockIdx.x;
  int t = threadIdx.x;
  size_t i0 = (size_t)row * 1024 + t * 4;
  bf16x4 a = *(const bf16x4*)(p0 + i0);
  bf16x4 b = *(const bf16x4*)(p1 + i0);
  float4 r = *(const float4*)(res + i0);
  float4 bi = ((const float4*)bias)[t];
  float v0 = (float)a[0] + (float)b[0] + bi.x + r.x;
  float v1 = (float)a[1] + (float)b[1] + bi.y + r.y;
  float v2 = (float)a[2] + (float)b[2] + bi.z + r.z;
  float v3 = (float)a[3] + (float)b[3] + bi.w + r.w;
  float4 vv = {v0, v1, v2, v3};
  *(float4*)(x1 + i0) = vv;
  float s  = v0 + v1 + v2 + v3;
  float sq = v0 * v0 + v1 * v1 + v2 * v2 + v3 * v3;
#pragma unroll
  for (int off = 32; off >= 1; off >>= 1) {
    s  += __shfl_xor(s, off);
    sq += __shfl_xor(sq, off);
  }
  __shared__ float ps[4], pq[4];
  if ((t & 63) == 0) { ps[t >> 6] = s; pq[t >> 6] = sq; }
  __syncthreads();
  s  = ps[0] + ps[1] + ps[2] + ps[3];
  sq = pq[0] + pq[1] + pq[2] + pq[3];
  float mu  = s * (1.f / 1024.f);
  float var = sq * (1.f / 1024.f) - mu * mu;
  float rstd = rsqrtf(var + 1e-5f);
  float4 wv = ((const float4*)lnw)[t];
  float4 bv = ((const float4*)lnb)[t];
  hout[i0 + 0] = (bf16)((v0 - mu) * rstd * wv.x + bv.x);
  hout[i0 + 1] = (bf16)((v1 - mu) * rstd * wv.y + bv.y);
  hout[i0 + 2] = (bf16)((v2 - mu) * rstd * wv.z + bv.z);
  hout[i0 + 3] = (bf16)((v3 - mu) * rstd * wv.w + bv.w);
}

// LayerNorm over last dim (1024), fp32 in -> bf16 out. One block per row.
__global__ __launch_bounds__(256)
void ln_bf16(const float* __restrict__ x, const float* __restrict__ w,
             const float* __restrict__ b, bf16* __restrict__ out)
{
  int row = blockIdx.x;
  int t = threadIdx.x;
  float4 v = ((const float4*)(x + (size_t)row * 1024))[t];
  float s  = v.x + v.y + v.z + v.w;
  float sq = v.x * v.x + v.y * v.y + v.z * v.z + v.w * v.w;
#pragma unroll
  for (int off = 32; off >= 1; off >>= 1) {
    s  += __shfl_xor(s, off);
    sq += __shfl_xor(sq, off);
  }
  __shared__ float ps[4], pq[4];
  if ((t & 63) == 0) { ps[t >> 6] = s; pq[t >> 6] = sq; }
  __syncthreads();
  s  = ps[0] + ps[1] + ps[2] + ps[3];
  sq = pq[0] + pq[1] + pq[2] + pq[3];
  float mu  = s * (1.f / 1024.f);
  float var = sq * (1.f / 1024.f) - mu * mu;
  float rstd = rsqrtf(var + 1e-5f);
  float4 wv = ((const float4*)w)[t];
  float4 bv = ((const float4*)b)[t];
  size_t o0 = (size_t)row * 1024 + t * 4;
  out[o0 + 0] = (bf16)((v.x - mu) * rstd * wv.x + bv.x);
  out[o0 + 1] = (bf16)((v.y - mu) * rstd * wv.y + bv.y);
  out[o0 + 2] = (bf16)((v.z - mu) * rstd * wv.z + bv.z);
  out[o0 + 3] = (bf16)((v.w - mu) * rstd * wv.w + bv.w);
}

// WT[N,K] (bf16) = W[K,N] (f32) transposed+cast. grid=(K/32, N/32), 256 thr.
__global__ __launch_bounds__(256)
void transpose_cast(const float* __restrict__ W, bf16* __restrict__ WT, int K, int N)
{
  __shared__ float tile[32][33];
  int bk = blockIdx.x * 32, bn = blockIdx.y * 32;
  int tx = threadIdx.x & 31, ty = threadIdx.x >> 5;
#pragma unroll
  for (int i = ty; i < 32; i += 8)
    tile[i][tx] = W[(size_t)(bk + i) * N + bn + tx];
  __syncthreads();
#pragma unroll
  for (int i = ty; i < 32; i += 8)
    WT[(size_t)(bn + i) * K + bk + tx] = (bf16)tile[tx][i];
}

// V transpose: vt[(b*16+h)*64 + d][t] = qkv[(b*2048+t)*3072 + 2048 + h*64 + d]
__global__ __launch_bounds__(256)
void vtrans(const bf16* __restrict__ qkv, bf16* __restrict__ vt)
{
  __shared__ alignas(16) bf16 tile[64 * 64];
  int bh = blockIdx.x;
  int b = bh >> 4, h = bh & 15;
  int t0 = blockIdx.y * 64;
  int t = threadIdx.x;
#pragma unroll
  for (int i = 0; i < 2; ++i) {
    int c = i * 256 + t;
    int tt = c >> 3, d8 = c & 7;
    bf16x8 v = *(const bf16x8*)(qkv + (size_t)(b * 2048 + t0 + tt) * 3072 + 2048 + h * 64 + d8 * 8);
    *(bf16x8*)&tile[(tt * 8 + (d8 ^ (tt >> 3))) * 8] = v;
  }
  __syncthreads();
#pragma unroll
  for (int i = 0; i < 2; ++i) {
    int c = i * 256 + t;
    int d = c >> 3, tt8 = c & 7;
    bf16x8 o;
#pragma unroll
    for (int j = 0; j < 8; ++j) {
      int row = tt8 * 8 + j;
      o[j] = tile[(row * 8 + ((d >> 3) ^ (row >> 3))) * 8 + (d & 7)];
    }
    *(bf16x8*)(vt + (size_t)(bh * 64 + d) * 2048 + t0 + tt8 * 8) = o;
  }
}

// Flash causal attention, 8-wave blocks (QBLK=128), fixed-cap softmax
// (Q pre-scaled by 0.125*log2e in qkv epilogue). Double-buffered K/V
// staging shared by 8 waves; single fused vmcnt(0)+barrier per tile.
__global__ __launch_bounds__(512)
void attn_flash(const bf16* __restrict__ qkv, const bf16* __restrict__ vt,
                bf16* __restrict__ y)
{
  __shared__ alignas(16) bf16 lk[2][4096];
  __shared__ alignas(16) bf16 lv[2][4096];
  __shared__ alignas(16) bf16 lp[8][16 * 64];

  int bid = blockIdx.x;
  int bh = bid & 63;
  int qb = 15 - (bid >> 6);            // big q-blocks first
  int b = bh >> 4, h = bh & 15;
  int t = threadIdx.x;
  int w = t >> 6, l = t & 63;
  int lr = l & 15, lg = l >> 4;
  int q0 = qb * 128;
  int qw = q0 + w * 16;
  const size_t RS = 3072;

  const bf16* qbase = qkv + (size_t)(b * 2048) * RS + h * 64;
  const bf16* kbase = qkv + (size_t)(b * 2048) * RS + 1024 + h * 64;
  const bf16* vtb   = vt + (size_t)(bh * 64) * 2048;

  bf16x8 qf[2];
#pragma unroll
  for (int kk = 0; kk < 2; ++kk)
    qf[kk] = *(const bf16x8*)(qbase + (size_t)(qw + lr) * RS + kk * 32 + lg * 8);

  // per-thread staging: 1 chunk of K-tile + 1 chunk of V^T-tile (512 thr)
  int row = t >> 3, c8 = t & 7;
  int sc8 = c8 ^ (row & 7);
  const bf16* pK = kbase + (size_t)row * RS + sc8 * 8;
  const bf16* pV = vtb + (size_t)row * 2048 + sc8 * 8;
  int dst = t * 8;

  f32x4 zero = {0.f, 0.f, 0.f, 0.f};
  f32x4 o[4];
#pragma unroll
  for (int ni = 0; ni < 4; ++ni) o[ni] = zero;
  float lo[4] = {0.f, 0.f, 0.f, 0.f};

  int nkb = 2 * qb + 2;
  gload_lds16(pK, &lk[0][dst]);
  gload_lds16(pV, &lv[0][dst]);

  for (int kb = 0; kb < nkb; ++kb) {
    int cur = kb & 1;
    int k0 = kb * 64;
    VM0_BAR();
    if (kb + 1 < nkb) {
      pK += 64 * RS;
      pV += 64;
      gload_lds16(pK, &lk[cur ^ 1][dst]);
      gload_lds16(pV, &lv[cur ^ 1][dst]);
    }

    f32x4 s[4];
#pragma unroll
    for (int j = 0; j < 4; ++j) s[j] = zero;
#pragma unroll
    for (int kk = 0; kk < 2; ++kk)
#pragma unroll
      for (int j = 0; j < 4; ++j) {
        int krow = j * 16 + lr;
        bf16x8 kf = *(const bf16x8*)&lk[cur][krow * 64 + (((4 * kk + lg) ^ (krow & 7)) * 8)];
        s[j] = MF(qf[kk], kf, s[j]);
      }

    bool needmask = (k0 + 63 > qw);    // wave-uniform
    float p[4][4];
#pragma unroll
    for (int r = 0; r < 4; ++r) {
      int tq = qw + lg * 4 + r;
#pragma unroll
      for (int j = 0; j < 4; ++j) {
        float v = s[j][r];
        if (needmask && (k0 + j * 16 + lr > tq)) v = -1e30f;
        p[j][r] = exp2f(v);
      }
      lo[r] += (p[0][r] + p[1][r]) + (p[2][r] + p[3][r]);
    }

#pragma unroll
    for (int r = 0; r < 4; ++r) {
      int qr = lg * 4 + r;
#pragma unroll
      for (int j = 0; j < 4; ++j) {
        int ch = (2 * j + (lr >> 3)) ^ (qr & 7);
        lp[w][qr * 64 + ch * 8 + (lr & 7)] = (bf16)p[j][r];
      }
    }
    bf16x8 pa[2];
#pragma unroll
    for (int kf = 0; kf < 2; ++kf)
      pa[kf] = *(const bf16x8*)&lp[w][lr * 64 + (((4 * kf + lg) ^ (lr & 7)) * 8)];

#pragma unroll
    for (int ni = 0; ni < 4; ++ni)
#pragma unroll
      for (int kf = 0; kf < 2; ++kf) {
        int d = ni * 16 + lr;
        bf16x8 vf = *(const bf16x8*)&lv[cur][d * 64 + (((4 * kf + lg) ^ (d & 7)) * 8)];
        o[ni] = MF(pa[kf], vf, o[ni]);
      }
  }

#pragma unroll
  for (int r = 0; r < 4; ++r) {
#pragma unroll
    for (int off = 1; off < 16; off <<= 1) lo[r] += __shfl_xor(lo[r], off);
    lo[r] = 1.f / lo[r];
  }
#pragma unroll
  for (int ni = 0; ni < 4; ++ni)
#pragma unroll
    for (int r = 0; r < 4; ++r) {
      int tq = qw + lg * 4 + r;
      y[(size_t)(b * 2048 + tq) * 1024 + h * 64 + ni * 16 + lr] = (bf16)(o[ni][r] * lo[r]);
    }
}

extern "C" void kernel_launch(void* const* d_in, const int* in_sizes, int n_in,
                              void* d_out, int out_size, void* d_ws, size_t ws_size,
                              hipStream_t stream) {
  (void)in_sizes; (void)n_in; (void)out_size; (void)ws_size;
  const float* x      = (const float*)d_in[0];
  const float* ln1w   = (const float*)d_in[1];
  const float* ln1b   = (const float*)d_in[2];
  const float* ln2w   = (const float*)d_in[3];
  const float* ln2b   = (const float*)d_in[4];
  const float* w_attn = (const float*)d_in[5];
  const float* b_attn = (const float*)d_in[6];
  const float* w_proj = (const float*)d_in[7];
  const float* b_proj = (const float*)d_in[8];
  const float* w_fc   = (const float*)d_in[9];
  const float* b_fc   = (const float*)d_in[10];
  const float* w_fc2  = (const float*)d_in[11];
  const float* b_fc2  = (const float*)d_in[12];
  float* out = (float*)d_out;

  // workspace: h | [qkv | y] == m | x1 (vt overlays x1) | weightsT
  char* p = (char*)d_ws;
  bf16*  h     = (bf16*)p;  p += (size_t)8192 * 1024 * 2;
  bf16*  qkv   = (bf16*)p;
  bf16*  mbuf  = (bf16*)p;  p += (size_t)8192 * 3072 * 2;   // m overlays qkv+y
  bf16*  ybuf  = (bf16*)p;  p += (size_t)8192 * 1024 * 2;
  float* x1    = (float*)p; p += (size_t)8192 * 1024 * 4;
  bf16*  wqkvT = (bf16*)p;  p += (size_t)3072 * 1024 * 2;
  bf16*  wprojT= (bf16*)p;  p += (size_t)1024 * 1024 * 2;
  bf16*  wfcT  = (bf16*)p;  p += (size_t)4096 * 1024 * 2;
  bf16*  wfc2T = (bf16*)p;  p += (size_t)1024 * 4096 * 2;
  bf16*  vt    = (bf16*)x1;       // dead until combine_ln writes x1
  bf16*  pp0   = qkv;             // proj split-K partials (qkv dead post-attn)
  bf16*  pp1   = qkv + (size_t)8192 * 1024;
  bf16*  sp0   = h;               // fc2 split-K partials
  bf16*  sp1   = wqkvT;

  transpose_cast<<<dim3(1024 / 32, 3072 / 32), 256, 0, stream>>>(w_attn, wqkvT, 1024, 3072);
  transpose_cast<<<dim3(1024 / 32, 1024 / 32), 256, 0, stream>>>(w_proj, wprojT, 1024, 1024);
  transpose_cast<<<dim3(1024 / 32, 4096 / 32), 256, 0, stream>>>(w_fc,   wfcT,  1024, 4096);
  transpose_cast<<<dim3(4096 / 32, 1024 / 32), 256, 0, stream>>>(w_fc2,  wfc2T, 4096, 1024);

  ln_bf16<<<8192, 256, 0, stream>>>(x, ln1w, ln1b, h);
  gemmq<4, 1><<<384, 512, 0, stream>>>(h, wqkvT, b_attn, nullptr, qkv, nullptr, 8192, 3072, 1024);
  vtrans<<<dim3(64, 32), 256, 0, stream>>>(qkv, vt);
  attn_flash<<<1024, 512, 0, stream>>>(qkv, vt, ybuf);
  gemmq<3, 2><<<256, 512, 0, stream>>>(ybuf, wprojT, nullptr, nullptr, pp0, pp1, 8192, 1024, 1024);
  combine_ln<<<8192, 256, 0, stream>>>(pp0, pp1, b_proj, x, ln2w, ln2b, x1, h);
  gemmq<2, 1><<<512, 512, 0, stream>>>(h, wfcT, b_fc, nullptr, mbuf, nullptr, 8192, 4096, 1024);
  gemmq<3, 2><<<256, 512, 0, stream>>>(mbuf, wfc2T, nullptr, nullptr, sp0, sp1, 8192, 1024, 4096);
  combine2<<<4096, 256, 0, stream>>>(sp0, sp1, b_fc2, x1, out);
}

// Round 15
// 394.819 us; speedup vs baseline: 2.5265x; 1.0666x over previous
//
#include <hip/hip_runtime.h>
#include <hip/hip_bf16.h>
#include <math.h>

typedef __bf16 bf16;
typedef __bf16 bf16x4 __attribute__((ext_vector_type(4)));
typedef __bf16 bf16x8 __attribute__((ext_vector_type(8)));
typedef float f32x4 __attribute__((ext_vector_type(4)));

__device__ __forceinline__ void gload_lds16(const bf16* g, bf16* l) {
  __builtin_amdgcn_global_load_lds(
      (const __attribute__((address_space(1))) void*)g,
      (__attribute__((address_space(3))) void*)l, 16, 0, 0);
}

#define MF(a, b, c) __builtin_amdgcn_mfma_f32_16x16x32_bf16((a), (b), (c), 0, 0, 0)
// fused wait+barrier blocks (opaque: no memory op can cross)
#define VM2_BAR()  asm volatile("s_waitcnt vmcnt(2)\ns_barrier" ::: "memory")
#define VM0_BAR()  asm volatile("s_waitcnt vmcnt(0)\ns_barrier" ::: "memory")

// 128x128 8-wave GEMM, BK=64, [128][64] LDS tiles (128B rows, 0-conflict
// chunk-XOR swizzle), double-buffered, 64KB LDS -> 2 blocks/CU co-resident
// (cross-block overlap hides barrier stalls; m114 mechanism). Per-wave
// output 64x32 (wave reads only its own A/B halves). 2 phases/tile:
//  ph0: VM2+bar -> read A-frags -> stage A-halves(T+1)
//  ph1: VM2+bar -> read B-frags -> stage B-halves(T+1) -> 16 MFMA
// Ledger (4 single-load stages/tile): steady VM2/VM2; tail VM2/VM0.
// C = A[M,K] @ BT[N,K]^T, bf16 in, fp32 accum.
// EPI 0: bf16 = acc+bias | 1: f32 = acc+bias+res | 2: bf16 = gelu(acc+bias)
// EPI 4: bf16 = (acc+bias)*(col<1024 ? 0.125*log2e : 1)
template <int EPI>
__global__ __launch_bounds__(512, 4)
void gemmk(const bf16* __restrict__ A, const bf16* __restrict__ BT,
           const float* __restrict__ bias, const float* __restrict__ res,
           void* __restrict__ Cout, int M, int N, int K)
{
  __shared__ alignas(16) bf16 lsA[2][8192];   // [buf][128*64] 16KB each
  __shared__ alignas(16) bf16 lsB[2][8192];

  int nbn = N >> 7;
  int nwg = (M >> 7) * nbn;
  int bid = blockIdx.x;
  int cpx = nwg >> 3;
  int wg  = (bid & 7) * cpx + (bid >> 3);      // XCD swizzle (bijective)
  int m0 = (wg / nbn) << 7;
  int n0 = (wg % nbn) << 7;

  int t = threadIdx.x;
  int l = t & 63, w = t >> 6;
  int gm = w >> 2;               // 0/1: A-half (64 rows) owned by this wave
  int gn = w & 3;                // 0..3: 32-col slice of B
  int lr = l & 15, lg = l >> 4;

  int nt = K >> 6;

  const bf16* Ag = A  + (size_t)m0 * K;
  const bf16* Bg = BT + (size_t)n0 * K;

  // ds_read element offsets: chunk8 = (kk*4+lg) ^ (row&7); row&7 == lr&7
  int swz0 = (lg ^ (lr & 7)) << 3;
  int swz1 = swz0 ^ 32;
  int aBase = (gm * 64 + lr) << 6;     // + mi*1024
  int bBase = (gn * 32 + lr) << 6;     // + ni*1024

  // staging: each half = 64 rows x 64 = 8KB = 1 chunk/thread (512 thr)
  int srow = t >> 3;
  int g = (t & 7) ^ (srow & 7);        // inverse-swizzled source chunk
  const bf16* sA0 = Ag + (size_t)srow * K + g * 8;
  const bf16* sA1 = Ag + (size_t)(64 + srow) * K + g * 8;
  const bf16* sB0 = Bg + (size_t)srow * K + g * 8;
  const bf16* sB1 = Bg + (size_t)(64 + srow) * K + g * 8;
  int dstE = t * 8;

  f32x4 acc[4][2];
  f32x4 zero = {0.f, 0.f, 0.f, 0.f};
#pragma unroll
  for (int mi = 0; mi < 4; ++mi)
#pragma unroll
    for (int ni = 0; ni < 2; ++ni) acc[mi][ni] = zero;

  // prologue: stage tile 0 in order A0,A1,B0,B1 (1 load each)
  gload_lds16(sA0, &lsA[0][dstE]);
  gload_lds16(sA1, &lsA[0][4096 + dstE]);
  gload_lds16(sB0, &lsB[0][dstE]);
  gload_lds16(sB1, &lsB[0][4096 + dstE]);

  bf16x8 af[4][2], bf[2][2];

  for (int T = 0; T < nt; ++T) {
    int c = T & 1, d = c ^ 1;
    bool st = (T + 1 < nt);
    int k64 = (T + 1) << 6;

    // ---- ph0: A-halves of tile T resident; read A-frags; stage A(T+1)
    VM2_BAR();
#pragma unroll
    for (int mi = 0; mi < 4; ++mi) {
      af[mi][0] = *(const bf16x8*)(&lsA[c][0] + aBase + mi * 1024 + swz0);
      af[mi][1] = *(const bf16x8*)(&lsA[c][0] + aBase + mi * 1024 + swz1);
    }
    if (st) {
      gload_lds16(sA0 + k64, &lsA[d][dstE]);
      gload_lds16(sA1 + k64, &lsA[d][4096 + dstE]);
    }

    // ---- ph1: B-halves of tile T resident; read B-frags; stage B(T+1);
    //      MFMA (consumes A-frags read a phase earlier + B-frags)
    if (st) VM2_BAR(); else VM0_BAR();
#pragma unroll
    for (int ni = 0; ni < 2; ++ni) {
      bf[ni][0] = *(const bf16x8*)(&lsB[c][0] + bBase + ni * 1024 + swz0);
      bf[ni][1] = *(const bf16x8*)(&lsB[c][0] + bBase + ni * 1024 + swz1);
    }
    if (st) {
      gload_lds16(sB0 + k64, &lsB[d][dstE]);
      gload_lds16(sB1 + k64, &lsB[d][4096 + dstE]);
    }
    __builtin_amdgcn_s_setprio(1);
#pragma unroll
    for (int mi = 0; mi < 4; ++mi)
#pragma unroll
      for (int ni = 0; ni < 2; ++ni)
#pragma unroll
        for (int kk = 0; kk < 2; ++kk)
          acc[mi][ni] = MF(af[mi][kk], bf[ni][kk], acc[mi][ni]);
    __builtin_amdgcn_s_setprio(0);
  }

  // epilogue: per wave 64 rows x 32 cols
  const float SCLQ = 0.18033688011112042f;   // 0.125 * log2(e)
  bf16* Pb = (bf16*)Cout;
#pragma unroll
  for (int mi = 0; mi < 4; ++mi) {
    int row = m0 + gm * 64 + mi * 16 + lg * 4;
#pragma unroll
    for (int ni = 0; ni < 2; ++ni) {
      int col = n0 + gn * 32 + ni * 16 + lr;
      float bv = bias[col];
      f32x4 a = acc[mi][ni];
#pragma unroll
      for (int r = 0; r < 4; ++r) {
        float v = a[r] + bv;
        size_t idx = (size_t)(row + r) * N + col;
        if (EPI == 0)      Pb[idx] = (bf16)v;
        else if (EPI == 1) ((float*)Cout)[idx] = v + res[idx];
        else if (EPI == 2) Pb[idx] = (bf16)(0.5f * v * (1.f + erff(v * 0.70710678118654752f)));
        else if (EPI == 4) Pb[idx] = (bf16)((col < 1024) ? v * SCLQ : v);
      }
    }
  }
}

// LayerNorm over last dim (1024), fp32 in -> bf16 out. One block per row.
__global__ __launch_bounds__(256)
void ln_bf16(const float* __restrict__ x, const float* __restrict__ w,
             const float* __restrict__ b, bf16* __restrict__ out)
{
  int row = blockIdx.x;
  int t = threadIdx.x;
  float4 v = ((const float4*)(x + (size_t)row * 1024))[t];
  float s  = v.x + v.y + v.z + v.w;
  float sq = v.x * v.x + v.y * v.y + v.z * v.z + v.w * v.w;
#pragma unroll
  for (int off = 32; off >= 1; off >>= 1) {
    s  += __shfl_xor(s, off);
    sq += __shfl_xor(sq, off);
  }
  __shared__ float ps[4], pq[4];
  if ((t & 63) == 0) { ps[t >> 6] = s; pq[t >> 6] = sq; }
  __syncthreads();
  s  = ps[0] + ps[1] + ps[2] + ps[3];
  sq = pq[0] + pq[1] + pq[2] + pq[3];
  float mu  = s * (1.f / 1024.f);
  float var = sq * (1.f / 1024.f) - mu * mu;
  float rstd = rsqrtf(var + 1e-5f);
  float4 wv = ((const float4*)w)[t];
  float4 bv = ((const float4*)b)[t];
  size_t o0 = (size_t)row * 1024 + t * 4;
  out[o0 + 0] = (bf16)((v.x - mu) * rstd * wv.x + bv.x);
  out[o0 + 1] = (bf16)((v.y - mu) * rstd * wv.y + bv.y);
  out[o0 + 2] = (bf16)((v.z - mu) * rstd * wv.z + bv.z);
  out[o0 + 3] = (bf16)((v.w - mu) * rstd * wv.w + bv.w);
}

// WT[N,K] (bf16) = W[K,N] (f32) transposed+cast. grid=(K/32, N/32), 256 thr.
__global__ __launch_bounds__(256)
void transpose_cast(const float* __restrict__ W, bf16* __restrict__ WT, int K, int N)
{
  __shared__ float tile[32][33];
  int bk = blockIdx.x * 32, bn = blockIdx.y * 32;
  int tx = threadIdx.x & 31, ty = threadIdx.x >> 5;
#pragma unroll
  for (int i = ty; i < 32; i += 8)
    tile[i][tx] = W[(size_t)(bk + i) * N + bn + tx];
  __syncthreads();
#pragma unroll
  for (int i = ty; i < 32; i += 8)
    WT[(size_t)(bn + i) * K + bk + tx] = (bf16)tile[tx][i];
}

// V transpose: vt[(b*16+h)*64 + d][t] = qkv[(b*2048+t)*3072 + 2048 + h*64 + d]
__global__ __launch_bounds__(256)
void vtrans(const bf16* __restrict__ qkv, bf16* __restrict__ vt)
{
  __shared__ alignas(16) bf16 tile[64 * 64];
  int bh = blockIdx.x;
  int b = bh >> 4, h = bh & 15;
  int t0 = blockIdx.y * 64;
  int t = threadIdx.x;
#pragma unroll
  for (int i = 0; i < 2; ++i) {
    int c = i * 256 + t;
    int tt = c >> 3, d8 = c & 7;
    bf16x8 v = *(const bf16x8*)(qkv + (size_t)(b * 2048 + t0 + tt) * 3072 + 2048 + h * 64 + d8 * 8);
    *(bf16x8*)&tile[(tt * 8 + (d8 ^ (tt >> 3))) * 8] = v;
  }
  __syncthreads();
#pragma unroll
  for (int i = 0; i < 2; ++i) {
    int c = i * 256 + t;
    int d = c >> 3, tt8 = c & 7;
    bf16x8 o;
#pragma unroll
    for (int j = 0; j < 8; ++j) {
      int row = tt8 * 8 + j;
      o[j] = tile[(row * 8 + ((d >> 3) ^ (row >> 3))) * 8 + (d & 7)];
    }
    *(bf16x8*)(vt + (size_t)(bh * 64 + d) * 2048 + t0 + tt8 * 8) = o;
  }
}

// Flash causal attention, 8-wave blocks (QBLK=128), fixed-cap softmax
// (Q pre-scaled by 0.125*log2e in qkv epilogue). Double-buffered K/V
// staging shared by 8 waves; single fused vmcnt(0)+barrier per tile.
__global__ __launch_bounds__(512)
void attn_flash(const bf16* __restrict__ qkv, const bf16* __restrict__ vt,
                bf16* __restrict__ y)
{
  __shared__ alignas(16) bf16 lk[2][4096];
  __shared__ alignas(16) bf16 lv[2][4096];
  __shared__ alignas(16) bf16 lp[8][16 * 64];

  int bid = blockIdx.x;
  int bh = bid & 63;
  int qb = 15 - (bid >> 6);            // big q-blocks first
  int b = bh >> 4, h = bh & 15;
  int t = threadIdx.x;
  int w = t >> 6, l = t & 63;
  int lr = l & 15, lg = l >> 4;
  int q0 = qb * 128;
  int qw = q0 + w * 16;
  const size_t RS = 3072;

  const bf16* qbase = qkv + (size_t)(b * 2048) * RS + h * 64;
  const bf16* kbase = qkv + (size_t)(b * 2048) * RS + 1024 + h * 64;
  const bf16* vtb   = vt + (size_t)(bh * 64) * 2048;

  bf16x8 qf[2];
#pragma unroll
  for (int kk = 0; kk < 2; ++kk)
    qf[kk] = *(const bf16x8*)(qbase + (size_t)(qw + lr) * RS + kk * 32 + lg * 8);

  // per-thread staging: 1 chunk of K-tile + 1 chunk of V^T-tile (512 thr)
  int row = t >> 3, c8 = t & 7;
  int sc8 = c8 ^ (row & 7);
  const bf16* pK = kbase + (size_t)row * RS + sc8 * 8;
  const bf16* pV = vtb + (size_t)row * 2048 + sc8 * 8;
  int dst = t * 8;

  f32x4 zero = {0.f, 0.f, 0.f, 0.f};
  f32x4 o[4];
#pragma unroll
  for (int ni = 0; ni < 4; ++ni) o[ni] = zero;
  float lo[4] = {0.f, 0.f, 0.f, 0.f};

  int nkb = 2 * qb + 2;
  gload_lds16(pK, &lk[0][dst]);
  gload_lds16(pV, &lv[0][dst]);

  for (int kb = 0; kb < nkb; ++kb) {
    int cur = kb & 1;
    int k0 = kb * 64;
    VM0_BAR();
    if (kb + 1 < nkb) {
      pK += 64 * RS;
      pV += 64;
      gload_lds16(pK, &lk[cur ^ 1][dst]);
      gload_lds16(pV, &lv[cur ^ 1][dst]);
    }

    f32x4 s[4];
#pragma unroll
    for (int j = 0; j < 4; ++j) s[j] = zero;
#pragma unroll
    for (int kk = 0; kk < 2; ++kk)
#pragma unroll
      for (int j = 0; j < 4; ++j) {
        int krow = j * 16 + lr;
        bf16x8 kf = *(const bf16x8*)&lk[cur][krow * 64 + (((4 * kk + lg) ^ (krow & 7)) * 8)];
        s[j] = MF(qf[kk], kf, s[j]);
      }

    bool needmask = (k0 + 63 > qw);    // wave-uniform
    float p[4][4];
#pragma unroll
    for (int r = 0; r < 4; ++r) {
      int tq = qw + lg * 4 + r;
#pragma unroll
      for (int j = 0; j < 4; ++j) {
        float v = s[j][r];
        if (needmask && (k0 + j * 16 + lr > tq)) v = -1e30f;
        p[j][r] = exp2f(v);
      }
      lo[r] += (p[0][r] + p[1][r]) + (p[2][r] + p[3][r]);
    }

#pragma unroll
    for (int r = 0; r < 4; ++r) {
      int qr = lg * 4 + r;
#pragma unroll
      for (int j = 0; j < 4; ++j) {
        int ch = (2 * j + (lr >> 3)) ^ (qr & 7);
        lp[w][qr * 64 + ch * 8 + (lr & 7)] = (bf16)p[j][r];
      }
    }
    bf16x8 pa[2];
#pragma unroll
    for (int kf = 0; kf < 2; ++kf)
      pa[kf] = *(const bf16x8*)&lp[w][lr * 64 + (((4 * kf + lg) ^ (lr & 7)) * 8)];

#pragma unroll
    for (int ni = 0; ni < 4; ++ni)
#pragma unroll
      for (int kf = 0; kf < 2; ++kf) {
        int d = ni * 16 + lr;
        bf16x8 vf = *(const bf16x8*)&lv[cur][d * 64 + (((4 * kf + lg) ^ (d & 7)) * 8)];
        o[ni] = MF(pa[kf], vf, o[ni]);
      }
  }

#pragma unroll
  for (int r = 0; r < 4; ++r) {
#pragma unroll
    for (int off = 1; off < 16; off <<= 1) lo[r] += __shfl_xor(lo[r], off);
    lo[r] = 1.f / lo[r];
  }
#pragma unroll
  for (int ni = 0; ni < 4; ++ni)
#pragma unroll
    for (int r = 0; r < 4; ++r) {
      int tq = qw + lg * 4 + r;
      y[(size_t)(b * 2048 + tq) * 1024 + h * 64 + ni * 16 + lr] = (bf16)(o[ni][r] * lo[r]);
    }
}

extern "C" void kernel_launch(void* const* d_in, const int* in_sizes, int n_in,
                              void* d_out, int out_size, void* d_ws, size_t ws_size,
                              hipStream_t stream) {
  (void)in_sizes; (void)n_in; (void)out_size; (void)ws_size;
  const float* x      = (const float*)d_in[0];
  const float* ln1w   = (const float*)d_in[1];
  const float* ln1b   = (const float*)d_in[2];
  const float* ln2w   = (const float*)d_in[3];
  const float* ln2b   = (const float*)d_in[4];
  const float* w_attn = (const float*)d_in[5];
  const float* b_attn = (const float*)d_in[6];
  const float* w_proj = (const float*)d_in[7];
  const float* b_proj = (const float*)d_in[8];
  const float* w_fc   = (const float*)d_in[9];
  const float* b_fc   = (const float*)d_in[10];
  const float* w_fc2  = (const float*)d_in[11];
  const float* b_fc2  = (const float*)d_in[12];
  float* out = (float*)d_out;

  // workspace: h | [qkv | y] == m | x1 (vt overlays x1) | weightsT
  char* p = (char*)d_ws;
  bf16*  h     = (bf16*)p;  p += (size_t)8192 * 1024 * 2;
  bf16*  qkv   = (bf16*)p;
  bf16*  mbuf  = (bf16*)p;  p += (size_t)8192 * 3072 * 2;   // m overlays qkv+y
  bf16*  ybuf  = (bf16*)p;  p += (size_t)8192 * 1024 * 2;
  float* x1    = (float*)p; p += (size_t)8192 * 1024 * 4;
  bf16*  wqkvT = (bf16*)p;  p += (size_t)3072 * 1024 * 2;
  bf16*  wprojT= (bf16*)p;  p += (size_t)1024 * 1024 * 2;
  bf16*  wfcT  = (bf16*)p;  p += (size_t)4096 * 1024 * 2;
  bf16*  wfc2T = (bf16*)p;  p += (size_t)1024 * 4096 * 2;
  bf16*  vt    = (bf16*)x1;       // dead until proj writes x1 (after attn)

  transpose_cast<<<dim3(1024 / 32, 3072 / 32), 256, 0, stream>>>(w_attn, wqkvT, 1024, 3072);
  transpose_cast<<<dim3(1024 / 32, 1024 / 32), 256, 0, stream>>>(w_proj, wprojT, 1024, 1024);
  transpose_cast<<<dim3(1024 / 32, 4096 / 32), 256, 0, stream>>>(w_fc,   wfcT,  1024, 4096);
  transpose_cast<<<dim3(4096 / 32, 1024 / 32), 256, 0, stream>>>(w_fc2,  wfc2T, 4096, 1024);

  ln_bf16<<<8192, 256, 0, stream>>>(x, ln1w, ln1b, h);
  gemmk<4><<<1536, 512, 0, stream>>>(h, wqkvT, b_attn, nullptr, qkv, 8192, 3072, 1024);
  vtrans<<<dim3(64, 32), 256, 0, stream>>>(qkv, vt);
  attn_flash<<<1024, 512, 0, stream>>>(qkv, vt, ybuf);
  gemmk<1><<<512, 512, 0, stream>>>(ybuf, wprojT, b_proj, x, x1, 8192, 1024, 1024);
  ln_bf16<<<8192, 256, 0, stream>>>(x1, ln2w, ln2b, h);
  gemmk<2><<<2048, 512, 0, stream>>>(h, wfcT, b_fc, nullptr, mbuf, 8192, 4096, 1024);
  gemmk<1><<<512, 512, 0, stream>>>(mbuf, wfc2T, b_fc2, x1, out, 8192, 1024, 4096);
}